// Round 12
// baseline (509.861 us; speedup 1.0000x reference)
//
#include <hip/hip_runtime.h>
#include <hip/hip_cooperative_groups.h>

namespace cg = cooperative_groups;

#define D 128
#define BR 128   // rows per block in fused kernel

typedef _Float16 f16;
typedef f16 f16x8 __attribute__((ext_vector_type(8)));
typedef float f32x4 __attribute__((ext_vector_type(4)));

// async global->LDS, 16B per lane; LDS dest = wave-uniform base + lane*16
__device__ __forceinline__ void gl_lds16(const f16* g, f16* l) {
    __builtin_amdgcn_global_load_lds(
        (const __attribute__((address_space(1))) void*)g,
        (__attribute__((address_space(3))) void*)l, 16, 0, 0);
}

__device__ __forceinline__ void cvt8(const float* s, f16* d) {
    const float4 v0 = *(const float4*)s;
    const float4 v1 = *(const float4*)(s + 4);
    f16x8 h;
    h[0] = (f16)v0.x; h[1] = (f16)v0.y; h[2] = (f16)v0.z; h[3] = (f16)v0.w;
    h[4] = (f16)v1.x; h[5] = (f16)v1.y; h[6] = (f16)v1.z; h[7] = (f16)v1.w;
    *(f16x8*)d = h;
}

// ONE cooperative kernel: phase0 zero-cnt + x->f16 + W->f16; phase1 degree count;
// phase2 exclusive scan (block b sums cnt[0..b*1024) directly); phase3 CSR fill.
__global__ __launch_bounds__(256)
void csr_prep_kernel(const float* __restrict__ x,
                     const float* __restrict__ Wl0, const float* __restrict__ Wr0,
                     const float* __restrict__ Wl1, const float* __restrict__ Wr1,
                     const int* __restrict__ src, const int* __restrict__ dst,
                     int* cnt, int* __restrict__ off, int* cursor,
                     int* __restrict__ adj,
                     f16* __restrict__ xh, f16* __restrict__ wh,
                     int n, int E, int nb) {
    cg::grid_group grid = cg::this_grid();
    __shared__ int bsum[4];
    __shared__ int wsx[4];
    const int t = threadIdx.x;
    const int gtid = blockIdx.x * 256 + t;
    const int gsz = gridDim.x * 256;
    const int nc4 = (n + 3) / 4;
    const int nx8 = n * D / 8;

    // ---- phase 0: zero cnt + convert x + convert 4 W ----
    {
        const int nw8 = 2048;                    // 16384/8 per W matrix
        const int total = nc4 + nx8 + 4 * nw8;
        for (int i = gtid; i < total; i += gsz) {
            if (i < nc4) {
                ((int4*)cnt)[i] = make_int4(0, 0, 0, 0);
            } else if (i < nc4 + nx8) {
                const int j = i - nc4;
                cvt8(x + (size_t)j * 8, xh + (size_t)j * 8);
            } else {
                const int j = i - nc4 - nx8;
                const int m = j >> 11, o = j & 2047;
                const float* Wsrc = (m == 0) ? Wl0 : (m == 1) ? Wr0
                                  : (m == 2) ? Wl1 : Wr1;
                cvt8(Wsrc + o * 8, wh + m * 16384 + o * 8);
            }
        }
    }
    grid.sync();
    // ---- phase 1: count degrees ----
    for (int e = gtid; e < E; e += gsz) atomicAdd(&cnt[dst[e]], 1);
    grid.sync();
    // ---- phase 2: exclusive scan (blocks [0, nb)) ----
    if ((int)blockIdx.x < nb) {
        const int lane = t & 63, wid = t >> 6;
        const int chunk0 = blockIdx.x * 1024;
        int s = 0;
        for (int i = t; i < chunk0; i += 256) s += cnt[i];
#pragma unroll
        for (int m = 1; m < 64; m <<= 1) s += __shfl_xor(s, m, 64);
        if (lane == 0) bsum[wid] = s;
        __syncthreads();
        const int base = bsum[0] + bsum[1] + bsum[2] + bsum[3];
        const int i0 = chunk0 + t * 4;
        int v[4]; int ls = 0;
#pragma unroll
        for (int j = 0; j < 4; ++j) {
            v[j] = (i0 + j < n) ? cnt[i0 + j] : 0; ls += v[j];
        }
        int incl = ls;
#pragma unroll
        for (int m = 1; m < 64; m <<= 1) {
            int u = __shfl_up(incl, m, 64);
            if (lane >= m) incl += u;
        }
        if (lane == 63) wsx[wid] = incl;
        __syncthreads();
        int woff = 0;
#pragma unroll
        for (int k = 0; k < 4; ++k) woff += (k < wid) ? wsx[k] : 0;
        int run = base + woff + incl - ls;
#pragma unroll
        for (int j = 0; j < 4; ++j) {
            if (i0 + j < n) { off[i0 + j] = run; cursor[i0 + j] = run; run += v[j]; }
        }
    }
    grid.sync();
    // ---- phase 3: CSR fill ----
    for (int e = gtid; e < E; e += gsz) {
        const int pos = atomicAdd(&cursor[dst[e]], 1);
        adj[pos] = src[e];
    }
}

// pull-mode mean aggregation (R9-proven shape), f16 in/out, f32 accumulate.
// 16 lanes per node (lane owns 8 cols = 16B), 4 nodes/wave, 16 nodes/block,
// 8-neighbor ILP, 8 blocks/CU for latency hiding.
__global__ __launch_bounds__(256, 8)
void aggregate_kernel(const f16* xin, const int* __restrict__ adj,
                      const int* __restrict__ off, const int* __restrict__ cnt,
                      f16* __restrict__ agg, int n) {
    const int node = blockIdx.x * 16 + (threadIdx.x >> 4);
    if (node >= n) return;
    const int lane = threadIdx.x & 15;
    const int deg = cnt[node];
    const int o = off[node];
    const f16* xp = xin + (lane << 3);
    float a0 = 0.f, a1 = 0.f, a2 = 0.f, a3 = 0.f;
    float a4 = 0.f, a5 = 0.f, a6 = 0.f, a7 = 0.f;
    int k = 0;
    for (; k + 8 <= deg; k += 8) {
        int sidx[8];
#pragma unroll
        for (int j = 0; j < 8; ++j) sidx[j] = adj[o + k + j];
#pragma unroll
        for (int j = 0; j < 8; ++j) {
            const f16x8 v = *(const f16x8*)(xp + (size_t)sidx[j] * D);
            a0 += (float)v[0]; a1 += (float)v[1]; a2 += (float)v[2]; a3 += (float)v[3];
            a4 += (float)v[4]; a5 += (float)v[5]; a6 += (float)v[6]; a7 += (float)v[7];
        }
    }
    for (; k + 4 <= deg; k += 4) {
        int sidx[4];
#pragma unroll
        for (int j = 0; j < 4; ++j) sidx[j] = adj[o + k + j];
#pragma unroll
        for (int j = 0; j < 4; ++j) {
            const f16x8 v = *(const f16x8*)(xp + (size_t)sidx[j] * D);
            a0 += (float)v[0]; a1 += (float)v[1]; a2 += (float)v[2]; a3 += (float)v[3];
            a4 += (float)v[4]; a5 += (float)v[5]; a6 += (float)v[6]; a7 += (float)v[7];
        }
    }
    for (; k < deg; ++k) {
        const f16x8 v = *(const f16x8*)(xp + (size_t)adj[o + k] * D);
        a0 += (float)v[0]; a1 += (float)v[1]; a2 += (float)v[2]; a3 += (float)v[3];
        a4 += (float)v[4]; a5 += (float)v[5]; a6 += (float)v[6]; a7 += (float)v[7];
    }
    const float s = 1.0f / (float)max(deg, 1);
    f16x8 r;
    r[0] = (f16)(a0 * s); r[1] = (f16)(a1 * s);
    r[2] = (f16)(a2 * s); r[3] = (f16)(a3 * s);
    r[4] = (f16)(a4 * s); r[5] = (f16)(a5 * s);
    r[6] = (f16)(a6 * s); r[7] = (f16)(a7 * s);
    *(f16x8*)(agg + (size_t)node * D + (lane << 3)) = r;
}

// fused: out = agg @ Wl^T + bl + xin @ Wr^T ; LayerNorm ; ReLU
// 512 threads = 8 waves; wave w owns rows [w*16, w*16+16) of the 128-row tile.
// Staging: global_load_lds width=16, LINEAR LDS dest + inverse-XOR-swizzled
// global source (granule kg ^= row&7); reads use the same involution.
template <bool LAST>
__global__ __launch_bounds__(512, 2)
void fused_kernel(const f16* __restrict__ aggh, const f16* xinh,
                  const f16* __restrict__ Whl, const float* __restrict__ bl,
                  const f16* __restrict__ Whr,
                  const float* __restrict__ gamma, const float* __restrict__ beta,
                  f16* yh, float* __restrict__ yf, int n) {
    extern __shared__ char lds_raw[];
    f16* As = (f16*)lds_raw;             // [128][128] swizzled (32 KB)
    f16* Ws = (f16*)(lds_raw + 32768);   // [128][128] swizzled (32 KB)
    const int tid = threadIdx.x;
    const int w = tid >> 6, l = tid & 63;
    const int c = l & 15, g = l >> 4;
    const int lrow = l >> 4, kgs = l & 15;
    const int row0 = blockIdx.x * BR;

    f32x4 acc[8];
#pragma unroll
    for (int jt = 0; jt < 8; ++jt) acc[jt] = (f32x4){0.f, 0.f, 0.f, 0.f};

    for (int pass = 0; pass < 2; ++pass) {
        if (pass) __syncthreads();       // all pass-0 LDS reads done before overwrite
        const f16* Ain = pass ? xinh : aggh;
        const f16* Win = pass ? Whr : Whl;
#pragma unroll
        for (int i = 0; i < 4; ++i) {
            const int rbase = i * 32 + w * 4;         // wave-uniform (w uniform in wave)
            const int row = rbase + lrow;
            const int kg = kgs ^ (row & 7);           // inverse swizzle on source
            int srow = row0 + row;
            if (srow >= n) srow = n - 1;              // clamp: garbage only feeds rows>=n
            gl_lds16(Ain + (size_t)srow * D + kg * 8, As + rbase * D);
            gl_lds16(Win + row * D + kg * 8, Ws + rbase * D);
        }
        __syncthreads();                 // drains vmcnt -> LDS tiles complete
#pragma unroll
        for (int ks = 0; ks < 4; ++ks) {
            const int ke = ks * 32 + g * 8;
            const int ar = w * 16 + c;
            const f16x8 av = *(const f16x8*)(As + ar * D + (ke ^ ((ar & 7) * 8)));
            f16x8 bv[8];
#pragma unroll
            for (int jt = 0; jt < 8; ++jt) {
                const int br = jt * 16 + c;
                bv[jt] = *(const f16x8*)(Ws + br * D + (ke ^ ((br & 7) * 8)));
            }
#pragma unroll
            for (int jt = 0; jt < 8; ++jt)
                acc[jt] = __builtin_amdgcn_mfma_f32_16x16x32_f16(
                    av, bv[jt], acc[jt], 0, 0, 0);
        }
    }

    // epilogue: bias + LayerNorm + ReLU. C/D layout: col=l&15, row=(l>>4)*4+reg.
    float bj[8], gj[8], btj[8];
#pragma unroll
    for (int jt = 0; jt < 8; ++jt) {
        const int j = jt * 16 + c;
        bj[jt] = bl[j]; gj[jt] = gamma[j]; btj[jt] = beta[j];
    }
#pragma unroll
    for (int reg = 0; reg < 4; ++reg) {
        float v[8]; float s1 = 0.f, s2 = 0.f;
#pragma unroll
        for (int jt = 0; jt < 8; ++jt) {
            v[jt] = acc[jt][reg] + bj[jt];
            s1 += v[jt];
            s2 = fmaf(v[jt], v[jt], s2);
        }
#pragma unroll
        for (int m = 1; m < 16; m <<= 1) {
            s1 += __shfl_xor(s1, m, 64);
            s2 += __shfl_xor(s2, m, 64);
        }
        const float mu = s1 * (1.f / 128.f);
        const float var = s2 * (1.f / 128.f) - mu * mu;
        const float rstd = rsqrtf(var + 1e-5f);
        const int row = row0 + w * 16 + g * 4 + reg;
        if (row < n) {
#pragma unroll
            for (int jt = 0; jt < 8; ++jt) {
                const float o = fmaxf((v[jt] - mu) * rstd * gj[jt] + btj[jt], 0.f);
                if (LAST) yf[(size_t)row * D + jt * 16 + c] = o;
                else      yh[(size_t)row * D + jt * 16 + c] = (f16)o;
            }
        }
    }
}

extern "C" void kernel_launch(void* const* d_in, const int* in_sizes, int n_in,
                              void* d_out, int out_size, void* d_ws, size_t ws_size,
                              hipStream_t stream) {
    const float* x   = (const float*)d_in[0];
    const int*   ei  = (const int*)d_in[1];
    int E = in_sizes[1] / 2;
    int n = in_sizes[0] / D;
    const int* srcp = ei;
    const int* dstp = ei + E;
    const float* Wl0 = (const float*)d_in[2];
    const float* bl0 = (const float*)d_in[3];
    const float* Wr0 = (const float*)d_in[4];
    const float* g0  = (const float*)d_in[5];
    const float* be0 = (const float*)d_in[6];
    const float* Wl1 = (const float*)d_in[7];
    const float* bl1 = (const float*)d_in[8];
    const float* Wr1 = (const float*)d_in[9];
    const float* g1  = (const float*)d_in[10];
    const float* be1 = (const float*)d_in[11];
    float* y = (float*)d_out;

    // workspace: cnt | off | cursor | adj | wh | aggh | xh(=y1h)
    char* ws = (char*)d_ws;
    const size_t aN = ((size_t)n * 4 + 255) & ~(size_t)255;
    const size_t aE = ((size_t)E * 4 + 255) & ~(size_t)255;
    const size_t aW = 4 * 16384 * 2;                       // 4 W matrices, f16
    const size_t aH = ((size_t)n * D * 2 + 255) & ~(size_t)255;
    int* cnt    = (int*)ws;
    int* off    = (int*)(ws + aN);
    int* cursor = (int*)(ws + 2 * aN);
    int* adj    = (int*)(ws + 3 * aN);
    f16* wh     = (f16*)(ws + 3 * aN + aE);
    f16* aggh   = (f16*)(ws + 3 * aN + aE + aW);
    f16* xh     = (f16*)(ws + 3 * aN + aE + aW + aH);
    const size_t need = 3 * aN + aE + aW + 2 * aH;
    if (ws_size < need) return;

    const int LDS_BYTES = 65536;
    hipFuncSetAttribute((const void*)fused_kernel<false>,
                        hipFuncAttributeMaxDynamicSharedMemorySize, LDS_BYTES);
    hipFuncSetAttribute((const void*)fused_kernel<true>,
                        hipFuncAttributeMaxDynamicSharedMemorySize, LDS_BYTES);

    const int gA = (n + 15) / 16;
    const int gF = (n + BR - 1) / BR;
    int nb = (n + 1023) / 1024;

    // one cooperative kernel: prep + count + scan + fill
    void* args[] = {(void*)&x, (void*)&Wl0, (void*)&Wr0, (void*)&Wl1, (void*)&Wr1,
                    (void*)&srcp, (void*)&dstp, (void*)&cnt, (void*)&off,
                    (void*)&cursor, (void*)&adj, (void*)&xh, (void*)&wh,
                    (void*)&n, (void*)&E, (void*)&nb};
    hipLaunchCooperativeKernel((const void*)csr_prep_kernel, dim3(1024), dim3(256),
                               args, 0, stream);

    // layer 1: aggregate(xh) -> aggh ; fused writes f16 y1 over xh (row-aliased safe)
    aggregate_kernel<<<gA, 256, 0, stream>>>(xh, adj, off, cnt, aggh, n);
    fused_kernel<false><<<gF, 512, LDS_BYTES, stream>>>(aggh, xh, wh, bl0,
                                                        wh + 16384, g0, be0,
                                                        xh, nullptr, n);
    // layer 2: aggregate(y1h=xh) -> aggh ; fused writes f32 d_out
    aggregate_kernel<<<gA, 256, 0, stream>>>(xh, adj, off, cnt, aggh, n);
    fused_kernel<true><<<gF, 512, LDS_BYTES, stream>>>(aggh, xh, wh + 32768, bl1,
                                                       wh + 49152, g1, be1,
                                                       nullptr, y, n);
}

// Round 13
// 171.057 us; speedup vs baseline: 2.9806x; 2.9806x over previous
//
#include <hip/hip_runtime.h>

#define D 128
#define BR 128   // rows per block in fused kernel

typedef _Float16 f16;
typedef f16 f16x8 __attribute__((ext_vector_type(8)));
typedef float f32x4 __attribute__((ext_vector_type(4)));

// async global->LDS, 16B per lane; LDS dest = wave-uniform base + lane*16
__device__ __forceinline__ void gl_lds16(const f16* g, f16* l) {
    __builtin_amdgcn_global_load_lds(
        (const __attribute__((address_space(1))) void*)g,
        (__attribute__((address_space(3))) void*)l, 16, 0, 0);
}

// merged prep: zero cnt (int4 chunks) + convert x -> f16 + convert 4 W -> f16
__global__ __launch_bounds__(256)
void prep_kernel(const float* __restrict__ x,
                 const float* __restrict__ Wl0, const float* __restrict__ Wr0,
                 const float* __restrict__ Wl1, const float* __restrict__ Wr1,
                 f16* __restrict__ xh, f16* __restrict__ wh,
                 int4* __restrict__ cnt4, int nc4, int nx8) {
    const int nw8 = 2048;                       // 16384/8 chunks per W matrix
    const int total = nc4 + nx8 + 4 * nw8;
    for (int i = blockIdx.x * 256 + threadIdx.x; i < total; i += gridDim.x * 256) {
        if (i < nc4) {
            cnt4[i] = make_int4(0, 0, 0, 0);
        } else if (i < nc4 + nx8) {
            const int j = i - nc4;
            const float4 v0 = *(const float4*)(x + (size_t)j * 8);
            const float4 v1 = *(const float4*)(x + (size_t)j * 8 + 4);
            f16x8 h;
            h[0] = (f16)v0.x; h[1] = (f16)v0.y; h[2] = (f16)v0.z; h[3] = (f16)v0.w;
            h[4] = (f16)v1.x; h[5] = (f16)v1.y; h[6] = (f16)v1.z; h[7] = (f16)v1.w;
            *(f16x8*)(xh + (size_t)j * 8) = h;
        } else {
            const int j = i - nc4 - nx8;
            const int m = j >> 11, o = j & 2047;
            const float* Wsrc = (m == 0) ? Wl0 : (m == 1) ? Wr0 : (m == 2) ? Wl1 : Wr1;
            const float4 v0 = *(const float4*)(Wsrc + o * 8);
            const float4 v1 = *(const float4*)(Wsrc + o * 8 + 4);
            f16x8 h;
            h[0] = (f16)v0.x; h[1] = (f16)v0.y; h[2] = (f16)v0.z; h[3] = (f16)v0.w;
            h[4] = (f16)v1.x; h[5] = (f16)v1.y; h[6] = (f16)v1.z; h[7] = (f16)v1.w;
            *(f16x8*)(wh + m * 16384 + o * 8) = h;
        }
    }
}

__global__ void count_kernel(const int* __restrict__ dst, int* __restrict__ cnt, int E) {
    int e = blockIdx.x * 256 + threadIdx.x;
    if (e < E) atomicAdd(&cnt[dst[e]], 1);
}

// single-dispatch exclusive scan: block b computes base = sum cnt[0..b*1024)
// directly (L2-resident, all blocks concurrent), then local scan of its chunk.
__global__ __launch_bounds__(256)
void scan_kernel(const int* __restrict__ cnt, int* __restrict__ off,
                 int* __restrict__ cursor, int n) {
    const int t = threadIdx.x;
    const int lane = t & 63, wid = t >> 6;
    const int chunk0 = blockIdx.x * 1024;
    __shared__ int bsum[4];
    __shared__ int wsx[4];
    int s = 0;
    for (int i = t; i < chunk0; i += 256) s += cnt[i];
#pragma unroll
    for (int m = 1; m < 64; m <<= 1) s += __shfl_xor(s, m, 64);
    if (lane == 0) bsum[wid] = s;
    __syncthreads();
    const int base = bsum[0] + bsum[1] + bsum[2] + bsum[3];
    const int i0 = chunk0 + t * 4;
    int v[4]; int ls = 0;
#pragma unroll
    for (int j = 0; j < 4; ++j) { v[j] = (i0 + j < n) ? cnt[i0 + j] : 0; ls += v[j]; }
    int incl = ls;
#pragma unroll
    for (int m = 1; m < 64; m <<= 1) {
        int u = __shfl_up(incl, m, 64);
        if (lane >= m) incl += u;
    }
    if (lane == 63) wsx[wid] = incl;
    __syncthreads();
    int woff = 0;
#pragma unroll
    for (int k = 0; k < 4; ++k) woff += (k < wid) ? wsx[k] : 0;
    int run = base + woff + incl - ls;
#pragma unroll
    for (int j = 0; j < 4; ++j) {
        if (i0 + j < n) { off[i0 + j] = run; cursor[i0 + j] = run; run += v[j]; }
    }
}

__global__ void fill_kernel(const int* __restrict__ src, const int* __restrict__ dst,
                            int* cursor, int* __restrict__ adj, int E) {
    int e = blockIdx.x * 256 + threadIdx.x;
    if (e < E) {
        int pos = atomicAdd(&cursor[dst[e]], 1);
        adj[pos] = src[e];
    }
}

// pull-mode mean aggregation, f16 in/out, f32 accumulate. (R9-proven shape)
// 16 lanes per node (lane owns 8 cols = 16B), 4 nodes/wave, 16 nodes/block,
// 8-neighbor ILP, 8 blocks/CU for latency hiding.
__global__ __launch_bounds__(256, 8)
void aggregate_kernel(const f16* xin, const int* __restrict__ adj,
                      const int* __restrict__ off, const int* __restrict__ cnt,
                      f16* __restrict__ agg, int n) {
    const int node = blockIdx.x * 16 + (threadIdx.x >> 4);
    if (node >= n) return;
    const int lane = threadIdx.x & 15;
    const int deg = cnt[node];
    const int o = off[node];
    const f16* xp = xin + (lane << 3);
    float a0 = 0.f, a1 = 0.f, a2 = 0.f, a3 = 0.f;
    float a4 = 0.f, a5 = 0.f, a6 = 0.f, a7 = 0.f;
    int k = 0;
    for (; k + 8 <= deg; k += 8) {
        int sidx[8];
#pragma unroll
        for (int j = 0; j < 8; ++j) sidx[j] = adj[o + k + j];
#pragma unroll
        for (int j = 0; j < 8; ++j) {
            const f16x8 v = *(const f16x8*)(xp + (size_t)sidx[j] * D);
            a0 += (float)v[0]; a1 += (float)v[1]; a2 += (float)v[2]; a3 += (float)v[3];
            a4 += (float)v[4]; a5 += (float)v[5]; a6 += (float)v[6]; a7 += (float)v[7];
        }
    }
    for (; k + 4 <= deg; k += 4) {
        int sidx[4];
#pragma unroll
        for (int j = 0; j < 4; ++j) sidx[j] = adj[o + k + j];
#pragma unroll
        for (int j = 0; j < 4; ++j) {
            const f16x8 v = *(const f16x8*)(xp + (size_t)sidx[j] * D);
            a0 += (float)v[0]; a1 += (float)v[1]; a2 += (float)v[2]; a3 += (float)v[3];
            a4 += (float)v[4]; a5 += (float)v[5]; a6 += (float)v[6]; a7 += (float)v[7];
        }
    }
    for (; k < deg; ++k) {
        const f16x8 v = *(const f16x8*)(xp + (size_t)adj[o + k] * D);
        a0 += (float)v[0]; a1 += (float)v[1]; a2 += (float)v[2]; a3 += (float)v[3];
        a4 += (float)v[4]; a5 += (float)v[5]; a6 += (float)v[6]; a7 += (float)v[7];
    }
    const float s = 1.0f / (float)max(deg, 1);
    f16x8 r;
    r[0] = (f16)(a0 * s); r[1] = (f16)(a1 * s);
    r[2] = (f16)(a2 * s); r[3] = (f16)(a3 * s);
    r[4] = (f16)(a4 * s); r[5] = (f16)(a5 * s);
    r[6] = (f16)(a6 * s); r[7] = (f16)(a7 * s);
    *(f16x8*)(agg + (size_t)node * D + (lane << 3)) = r;
}

// fused: out = agg @ Wl^T + bl + xin @ Wr^T ; LayerNorm ; ReLU  (R9-proven shape)
// 512 threads = 8 waves; wave w owns rows [w*16, w*16+16) of the 128-row tile.
// Staging: global_load_lds width=16, LINEAR LDS dest + inverse-XOR-swizzled
// global source (granule kg ^= row&7); reads use the same involution.
template <bool LAST>
__global__ __launch_bounds__(512, 2)
void fused_kernel(const f16* __restrict__ aggh, const f16* xinh,
                  const f16* __restrict__ Whl, const float* __restrict__ bl,
                  const f16* __restrict__ Whr,
                  const float* __restrict__ gamma, const float* __restrict__ beta,
                  f16* yh, float* __restrict__ yf, int n) {
    extern __shared__ char lds_raw[];
    f16* As = (f16*)lds_raw;             // [128][128] swizzled (32 KB)
    f16* Ws = (f16*)(lds_raw + 32768);   // [128][128] swizzled (32 KB)
    const int tid = threadIdx.x;
    const int w = tid >> 6, l = tid & 63;
    const int c = l & 15, g = l >> 4;
    const int lrow = l >> 4, kgs = l & 15;
    const int row0 = blockIdx.x * BR;

    f32x4 acc[8];
#pragma unroll
    for (int jt = 0; jt < 8; ++jt) acc[jt] = (f32x4){0.f, 0.f, 0.f, 0.f};

    for (int pass = 0; pass < 2; ++pass) {
        if (pass) __syncthreads();       // all pass-0 LDS reads done before overwrite
        const f16* Ain = pass ? xinh : aggh;
        const f16* Win = pass ? Whr : Whl;
#pragma unroll
        for (int i = 0; i < 4; ++i) {
            const int rbase = i * 32 + w * 4;         // wave-uniform (w uniform in wave)
            const int row = rbase + lrow;
            const int kg = kgs ^ (row & 7);           // inverse swizzle on source
            int srow = row0 + row;
            if (srow >= n) srow = n - 1;              // clamp: garbage only feeds rows>=n
            gl_lds16(Ain + (size_t)srow * D + kg * 8, As + rbase * D);
            gl_lds16(Win + row * D + kg * 8, Ws + rbase * D);
        }
        __syncthreads();                 // drains vmcnt -> LDS tiles complete
#pragma unroll
        for (int ks = 0; ks < 4; ++ks) {
            const int ke = ks * 32 + g * 8;
            const int ar = w * 16 + c;
            const f16x8 av = *(const f16x8*)(As + ar * D + (ke ^ ((ar & 7) * 8)));
            f16x8 bv[8];
#pragma unroll
            for (int jt = 0; jt < 8; ++jt) {
                const int br = jt * 16 + c;
                bv[jt] = *(const f16x8*)(Ws + br * D + (ke ^ ((br & 7) * 8)));
            }
#pragma unroll
            for (int jt = 0; jt < 8; ++jt)
                acc[jt] = __builtin_amdgcn_mfma_f32_16x16x32_f16(
                    av, bv[jt], acc[jt], 0, 0, 0);
        }
    }

    // epilogue: bias + LayerNorm + ReLU. C/D layout: col=l&15, row=(l>>4)*4+reg.
    float bj[8], gj[8], btj[8];
#pragma unroll
    for (int jt = 0; jt < 8; ++jt) {
        const int j = jt * 16 + c;
        bj[jt] = bl[j]; gj[jt] = gamma[j]; btj[jt] = beta[j];
    }
#pragma unroll
    for (int reg = 0; reg < 4; ++reg) {
        float v[8]; float s1 = 0.f, s2 = 0.f;
#pragma unroll
        for (int jt = 0; jt < 8; ++jt) {
            v[jt] = acc[jt][reg] + bj[jt];
            s1 += v[jt];
            s2 = fmaf(v[jt], v[jt], s2);
        }
#pragma unroll
        for (int m = 1; m < 16; m <<= 1) {
            s1 += __shfl_xor(s1, m, 64);
            s2 += __shfl_xor(s2, m, 64);
        }
        const float mu = s1 * (1.f / 128.f);
        const float var = s2 * (1.f / 128.f) - mu * mu;
        const float rstd = rsqrtf(var + 1e-5f);
        const int row = row0 + w * 16 + g * 4 + reg;
        if (row < n) {
#pragma unroll
            for (int jt = 0; jt < 8; ++jt) {
                const float o = fmaxf((v[jt] - mu) * rstd * gj[jt] + btj[jt], 0.f);
                if (LAST) yf[(size_t)row * D + jt * 16 + c] = o;
                else      yh[(size_t)row * D + jt * 16 + c] = (f16)o;
            }
        }
    }
}

extern "C" void kernel_launch(void* const* d_in, const int* in_sizes, int n_in,
                              void* d_out, int out_size, void* d_ws, size_t ws_size,
                              hipStream_t stream) {
    const float* x   = (const float*)d_in[0];
    const int*   ei  = (const int*)d_in[1];
    const int E = in_sizes[1] / 2;
    const int n = in_sizes[0] / D;
    const int* srcp = ei;
    const int* dstp = ei + E;
    const float* Wl0 = (const float*)d_in[2];
    const float* bl0 = (const float*)d_in[3];
    const float* Wr0 = (const float*)d_in[4];
    const float* g0  = (const float*)d_in[5];
    const float* be0 = (const float*)d_in[6];
    const float* Wl1 = (const float*)d_in[7];
    const float* bl1 = (const float*)d_in[8];
    const float* Wr1 = (const float*)d_in[9];
    const float* g1  = (const float*)d_in[10];
    const float* be1 = (const float*)d_in[11];
    float* y = (float*)d_out;

    // workspace: cnt | off | cursor | adj | wh | aggh | xh(=y1h)
    char* ws = (char*)d_ws;
    const size_t aN = ((size_t)n * 4 + 255) & ~(size_t)255;
    const size_t aE = ((size_t)E * 4 + 255) & ~(size_t)255;
    const size_t aW = 4 * 16384 * 2;                       // 4 W matrices, f16
    const size_t aH = ((size_t)n * D * 2 + 255) & ~(size_t)255;
    int* cnt    = (int*)ws;
    int* off    = (int*)(ws + aN);
    int* cursor = (int*)(ws + 2 * aN);
    int* adj    = (int*)(ws + 3 * aN);
    f16* wh     = (f16*)(ws + 3 * aN + aE);
    f16* aggh   = (f16*)(ws + 3 * aN + aE + aW);
    f16* xh     = (f16*)(ws + 3 * aN + aE + aW + aH);
    const size_t need = 3 * aN + aE + aW + 2 * aH;
    if (ws_size < need) return;

    const int LDS_BYTES = 65536;
    hipFuncSetAttribute((const void*)fused_kernel<false>,
                        hipFuncAttributeMaxDynamicSharedMemorySize, LDS_BYTES);
    hipFuncSetAttribute((const void*)fused_kernel<true>,
                        hipFuncAttributeMaxDynamicSharedMemorySize, LDS_BYTES);

    const int gE = (E + 255) / 256;
    const int gA = (n + 15) / 16;
    const int gF = (n + BR - 1) / BR;
    const int nb = (n + 1023) / 1024;
    const int nc4 = (n + 3) / 4;
    const int nx8 = n * D / 8;

    // prep: zero cnt + x->f16 + W->f16 (one kernel), then CSR chain
    prep_kernel<<<1024, 256, 0, stream>>>(x, Wl0, Wr0, Wl1, Wr1, xh, wh,
                                          (int4*)cnt, nc4, nx8);
    count_kernel<<<gE, 256, 0, stream>>>(dstp, cnt, E);
    scan_kernel<<<nb, 256, 0, stream>>>(cnt, off, cursor, n);
    fill_kernel<<<gE, 256, 0, stream>>>(srcp, dstp, cursor, adj, E);

    // layer 1: aggregate(xh) -> aggh ; fused writes f16 y1 over xh (row-aliased safe)
    aggregate_kernel<<<gA, 256, 0, stream>>>(xh, adj, off, cnt, aggh, n);
    fused_kernel<false><<<gF, 512, LDS_BYTES, stream>>>(aggh, xh, wh, bl0,
                                                        wh + 16384, g0, be0,
                                                        xh, nullptr, n);
    // layer 2: aggregate(y1h=xh) -> aggh ; fused writes f32 d_out
    aggregate_kernel<<<gA, 256, 0, stream>>>(xh, adj, off, cnt, aggh, n);
    fused_kernel<true><<<gF, 512, LDS_BYTES, stream>>>(aggh, xh, wh + 32768, bl1,
                                                       wh + 49152, g1, be1,
                                                       nullptr, y, n);
}

// Round 14
// 145.828 us; speedup vs baseline: 3.4963x; 1.1730x over previous
//
#include <hip/hip_runtime.h>

#define D 128
#define BR 128   // rows per block in fused kernel

typedef _Float16 f16;
typedef f16 f16x8 __attribute__((ext_vector_type(8)));
typedef float f32x4 __attribute__((ext_vector_type(4)));
typedef unsigned short u16;

// async global->LDS, 16B per lane; LDS dest = wave-uniform base + lane*16
__device__ __forceinline__ void gl_lds16(const f16* g, f16* l) {
    __builtin_amdgcn_global_load_lds(
        (const __attribute__((address_space(1))) void*)g,
        (__attribute__((address_space(3))) void*)l, 16, 0, 0);
}

// merged prep: zero cnt (int4 chunks) + convert x -> f16 + convert 4 W -> f16
__global__ __launch_bounds__(256)
void prep_kernel(const float* __restrict__ x,
                 const float* __restrict__ Wl0, const float* __restrict__ Wr0,
                 const float* __restrict__ Wl1, const float* __restrict__ Wr1,
                 f16* __restrict__ xh, f16* __restrict__ wh,
                 int4* __restrict__ cnt4, int nc4, int nx8) {
    const int nw8 = 2048;                       // 16384/8 chunks per W matrix
    const int total = nc4 + nx8 + 4 * nw8;
    for (int i = blockIdx.x * 256 + threadIdx.x; i < total; i += gridDim.x * 256) {
        if (i < nc4) {
            cnt4[i] = make_int4(0, 0, 0, 0);
        } else if (i < nc4 + nx8) {
            const int j = i - nc4;
            const float4 v0 = *(const float4*)(x + (size_t)j * 8);
            const float4 v1 = *(const float4*)(x + (size_t)j * 8 + 4);
            f16x8 h;
            h[0] = (f16)v0.x; h[1] = (f16)v0.y; h[2] = (f16)v0.z; h[3] = (f16)v0.w;
            h[4] = (f16)v1.x; h[5] = (f16)v1.y; h[6] = (f16)v1.z; h[7] = (f16)v1.w;
            *(f16x8*)(xh + (size_t)j * 8) = h;
        } else {
            const int j = i - nc4 - nx8;
            const int m = j >> 11, o = j & 2047;
            const float* Wsrc = (m == 0) ? Wl0 : (m == 1) ? Wr0 : (m == 2) ? Wl1 : Wr1;
            const float4 v0 = *(const float4*)(Wsrc + o * 8);
            const float4 v1 = *(const float4*)(Wsrc + o * 8 + 4);
            f16x8 h;
            h[0] = (f16)v0.x; h[1] = (f16)v0.y; h[2] = (f16)v0.z; h[3] = (f16)v0.w;
            h[4] = (f16)v1.x; h[5] = (f16)v1.y; h[6] = (f16)v1.z; h[7] = (f16)v1.w;
            *(f16x8*)(wh + m * 16384 + o * 8) = h;
        }
    }
}

__global__ void count_kernel(const int* __restrict__ dst, int* __restrict__ cnt, int E) {
    int e = blockIdx.x * 256 + threadIdx.x;
    if (e < E) atomicAdd(&cnt[dst[e]], 1);
}

// ---- 2-dispatch exclusive scan (R9-proven): scan1 block sums; scan3 base+local ----
__global__ __launch_bounds__(256)
void scan1_kernel(const int* __restrict__ cnt, int* __restrict__ part, int n) {
    const int t = threadIdx.x;
    const int i0 = blockIdx.x * 1024 + t * 4;
    int s = 0;
#pragma unroll
    for (int j = 0; j < 4; ++j) { int i = i0 + j; if (i < n) s += cnt[i]; }
#pragma unroll
    for (int m = 1; m < 64; m <<= 1) s += __shfl_xor(s, m, 64);
    __shared__ int ws[4];
    if ((t & 63) == 0) ws[t >> 6] = s;
    __syncthreads();
    if (t == 0) part[blockIdx.x] = ws[0] + ws[1] + ws[2] + ws[3];
}

__global__ __launch_bounds__(256)
void scan3_kernel(const int* __restrict__ cnt, const int* __restrict__ part,
                  int* __restrict__ off, int* __restrict__ cursor, int n, int nb) {
    const int t = threadIdx.x;
    const int lane = t & 63, wid = t >> 6;
    __shared__ int s_base;
    if (t < 64) {                     // sum of part[j] for j < blockIdx.x
        int s = 0;
        for (int base = 0; base < nb; base += 64) {
            const int idx = base + lane;
            if (idx < nb && idx < (int)blockIdx.x) s += part[idx];
        }
#pragma unroll
        for (int m = 1; m < 64; m <<= 1) s += __shfl_xor(s, m, 64);
        if (lane == 0) s_base = s;
    }
    const int i0 = blockIdx.x * 1024 + t * 4;
    int v[4]; int s = 0;
#pragma unroll
    for (int j = 0; j < 4; ++j) { v[j] = (i0 + j < n) ? cnt[i0 + j] : 0; s += v[j]; }
    int incl = s;
#pragma unroll
    for (int m = 1; m < 64; m <<= 1) {
        int u = __shfl_up(incl, m, 64);
        if (lane >= m) incl += u;
    }
    __shared__ int ws[4];
    if (lane == 63) ws[wid] = incl;
    __syncthreads();
    int woff = 0;
#pragma unroll
    for (int k = 0; k < 4; ++k) woff += (k < wid) ? ws[k] : 0;
    int run = s_base + woff + incl - s;
#pragma unroll
    for (int j = 0; j < 4; ++j) {
        if (i0 + j < n) { off[i0 + j] = run; cursor[i0 + j] = run; run += v[j]; }
    }
}

// adj stored as u16 (src node ids < 65536): halves the scattered-write footprint
__global__ void fill_kernel(const int* __restrict__ src, const int* __restrict__ dst,
                            int* cursor, u16* __restrict__ adj, int E) {
    int e = blockIdx.x * 256 + threadIdx.x;
    if (e < E) {
        int pos = atomicAdd(&cursor[dst[e]], 1);
        adj[pos] = (u16)src[e];
    }
}

// pull-mode mean aggregation, f16 in/out, f32 accumulate. (R9-proven shape)
// 16 lanes per node (lane owns 8 cols = 16B), 4 nodes/wave, 16 nodes/block,
// 8-neighbor ILP, 8 blocks/CU for latency hiding.
__global__ __launch_bounds__(256, 8)
void aggregate_kernel(const f16* xin, const u16* __restrict__ adj,
                      const int* __restrict__ off, const int* __restrict__ cnt,
                      f16* __restrict__ agg, int n) {
    const int node = blockIdx.x * 16 + (threadIdx.x >> 4);
    if (node >= n) return;
    const int lane = threadIdx.x & 15;
    const int deg = cnt[node];
    const int o = off[node];
    const f16* xp = xin + (lane << 3);
    float a0 = 0.f, a1 = 0.f, a2 = 0.f, a3 = 0.f;
    float a4 = 0.f, a5 = 0.f, a6 = 0.f, a7 = 0.f;
    int k = 0;
    for (; k + 8 <= deg; k += 8) {
        int sidx[8];
#pragma unroll
        for (int j = 0; j < 8; ++j) sidx[j] = adj[o + k + j];
#pragma unroll
        for (int j = 0; j < 8; ++j) {
            const f16x8 v = *(const f16x8*)(xp + (size_t)sidx[j] * D);
            a0 += (float)v[0]; a1 += (float)v[1]; a2 += (float)v[2]; a3 += (float)v[3];
            a4 += (float)v[4]; a5 += (float)v[5]; a6 += (float)v[6]; a7 += (float)v[7];
        }
    }
    for (; k + 4 <= deg; k += 4) {
        int sidx[4];
#pragma unroll
        for (int j = 0; j < 4; ++j) sidx[j] = adj[o + k + j];
#pragma unroll
        for (int j = 0; j < 4; ++j) {
            const f16x8 v = *(const f16x8*)(xp + (size_t)sidx[j] * D);
            a0 += (float)v[0]; a1 += (float)v[1]; a2 += (float)v[2]; a3 += (float)v[3];
            a4 += (float)v[4]; a5 += (float)v[5]; a6 += (float)v[6]; a7 += (float)v[7];
        }
    }
    for (; k < deg; ++k) {
        const f16x8 v = *(const f16x8*)(xp + (size_t)adj[o + k] * D);
        a0 += (float)v[0]; a1 += (float)v[1]; a2 += (float)v[2]; a3 += (float)v[3];
        a4 += (float)v[4]; a5 += (float)v[5]; a6 += (float)v[6]; a7 += (float)v[7];
    }
    const float s = 1.0f / (float)max(deg, 1);
    f16x8 r;
    r[0] = (f16)(a0 * s); r[1] = (f16)(a1 * s);
    r[2] = (f16)(a2 * s); r[3] = (f16)(a3 * s);
    r[4] = (f16)(a4 * s); r[5] = (f16)(a5 * s);
    r[6] = (f16)(a6 * s); r[7] = (f16)(a7 * s);
    *(f16x8*)(agg + (size_t)node * D + (lane << 3)) = r;
}

// fused: out = agg @ Wl^T + bl + xin @ Wr^T ; LayerNorm ; ReLU  (R9-proven shape)
// 512 threads = 8 waves; wave w owns rows [w*16, w*16+16) of the 128-row tile.
// Staging: global_load_lds width=16, LINEAR LDS dest + inverse-XOR-swizzled
// global source (granule kg ^= row&7); reads use the same involution.
template <bool LAST>
__global__ __launch_bounds__(512, 2)
void fused_kernel(const f16* __restrict__ aggh, const f16* xinh,
                  const f16* __restrict__ Whl, const float* __restrict__ bl,
                  const f16* __restrict__ Whr,
                  const float* __restrict__ gamma, const float* __restrict__ beta,
                  f16* yh, float* __restrict__ yf, int n) {
    extern __shared__ char lds_raw[];
    f16* As = (f16*)lds_raw;             // [128][128] swizzled (32 KB)
    f16* Ws = (f16*)(lds_raw + 32768);   // [128][128] swizzled (32 KB)
    const int tid = threadIdx.x;
    const int w = tid >> 6, l = tid & 63;
    const int c = l & 15, g = l >> 4;
    const int lrow = l >> 4, kgs = l & 15;
    const int row0 = blockIdx.x * BR;

    f32x4 acc[8];
#pragma unroll
    for (int jt = 0; jt < 8; ++jt) acc[jt] = (f32x4){0.f, 0.f, 0.f, 0.f};

    for (int pass = 0; pass < 2; ++pass) {
        if (pass) __syncthreads();       // all pass-0 LDS reads done before overwrite
        const f16* Ain = pass ? xinh : aggh;
        const f16* Win = pass ? Whr : Whl;
#pragma unroll
        for (int i = 0; i < 4; ++i) {
            const int rbase = i * 32 + w * 4;         // wave-uniform (w uniform in wave)
            const int row = rbase + lrow;
            const int kg = kgs ^ (row & 7);           // inverse swizzle on source
            int srow = row0 + row;
            if (srow >= n) srow = n - 1;              // clamp: garbage only feeds rows>=n
            gl_lds16(Ain + (size_t)srow * D + kg * 8, As + rbase * D);
            gl_lds16(Win + row * D + kg * 8, Ws + rbase * D);
        }
        __syncthreads();                 // drains vmcnt -> LDS tiles complete
#pragma unroll
        for (int ks = 0; ks < 4; ++ks) {
            const int ke = ks * 32 + g * 8;
            const int ar = w * 16 + c;
            const f16x8 av = *(const f16x8*)(As + ar * D + (ke ^ ((ar & 7) * 8)));
            f16x8 bv[8];
#pragma unroll
            for (int jt = 0; jt < 8; ++jt) {
                const int br = jt * 16 + c;
                bv[jt] = *(const f16x8*)(Ws + br * D + (ke ^ ((br & 7) * 8)));
            }
#pragma unroll
            for (int jt = 0; jt < 8; ++jt)
                acc[jt] = __builtin_amdgcn_mfma_f32_16x16x32_f16(
                    av, bv[jt], acc[jt], 0, 0, 0);
        }
    }

    // epilogue: bias + LayerNorm + ReLU. C/D layout: col=l&15, row=(l>>4)*4+reg.
    float bj[8], gj[8], btj[8];
#pragma unroll
    for (int jt = 0; jt < 8; ++jt) {
        const int j = jt * 16 + c;
        bj[jt] = bl[j]; gj[jt] = gamma[j]; btj[jt] = beta[j];
    }
#pragma unroll
    for (int reg = 0; reg < 4; ++reg) {
        float v[8]; float s1 = 0.f, s2 = 0.f;
#pragma unroll
        for (int jt = 0; jt < 8; ++jt) {
            v[jt] = acc[jt][reg] + bj[jt];
            s1 += v[jt];
            s2 = fmaf(v[jt], v[jt], s2);
        }
#pragma unroll
        for (int m = 1; m < 16; m <<= 1) {
            s1 += __shfl_xor(s1, m, 64);
            s2 += __shfl_xor(s2, m, 64);
        }
        const float mu = s1 * (1.f / 128.f);
        const float var = s2 * (1.f / 128.f) - mu * mu;
        const float rstd = rsqrtf(var + 1e-5f);
        const int row = row0 + w * 16 + g * 4 + reg;
        if (row < n) {
#pragma unroll
            for (int jt = 0; jt < 8; ++jt) {
                const float o = fmaxf((v[jt] - mu) * rstd * gj[jt] + btj[jt], 0.f);
                if (LAST) yf[(size_t)row * D + jt * 16 + c] = o;
                else      yh[(size_t)row * D + jt * 16 + c] = (f16)o;
            }
        }
    }
}

extern "C" void kernel_launch(void* const* d_in, const int* in_sizes, int n_in,
                              void* d_out, int out_size, void* d_ws, size_t ws_size,
                              hipStream_t stream) {
    const float* x   = (const float*)d_in[0];
    const int*   ei  = (const int*)d_in[1];
    const int E = in_sizes[1] / 2;
    const int n = in_sizes[0] / D;
    const int* srcp = ei;
    const int* dstp = ei + E;
    const float* Wl0 = (const float*)d_in[2];
    const float* bl0 = (const float*)d_in[3];
    const float* Wr0 = (const float*)d_in[4];
    const float* g0  = (const float*)d_in[5];
    const float* be0 = (const float*)d_in[6];
    const float* Wl1 = (const float*)d_in[7];
    const float* bl1 = (const float*)d_in[8];
    const float* Wr1 = (const float*)d_in[9];
    const float* g1  = (const float*)d_in[10];
    const float* be1 = (const float*)d_in[11];
    float* y = (float*)d_out;

    // workspace: cnt | off | cursor | part | adj(u16) | wh | aggh | xh(=y1h)
    char* ws = (char*)d_ws;
    const size_t aN = ((size_t)n * 4 + 255) & ~(size_t)255;
    const size_t aE = ((size_t)E * 2 + 255) & ~(size_t)255;    // u16 adj
    const size_t aP = 4096;
    const size_t aW = 4 * 16384 * 2;                           // 4 W matrices, f16
    const size_t aH = ((size_t)n * D * 2 + 255) & ~(size_t)255;
    int* cnt    = (int*)ws;
    int* off    = (int*)(ws + aN);
    int* cursor = (int*)(ws + 2 * aN);
    int* part   = (int*)(ws + 3 * aN);
    u16* adj    = (u16*)(ws + 3 * aN + aP);
    f16* wh     = (f16*)(ws + 3 * aN + aP + aE);
    f16* aggh   = (f16*)(ws + 3 * aN + aP + aE + aW);
    f16* xh     = (f16*)(ws + 3 * aN + aP + aE + aW + aH);
    const size_t need = 3 * aN + aP + aE + aW + 2 * aH;
    if (ws_size < need) return;

    const int LDS_BYTES = 65536;
    hipFuncSetAttribute((const void*)fused_kernel<false>,
                        hipFuncAttributeMaxDynamicSharedMemorySize, LDS_BYTES);
    hipFuncSetAttribute((const void*)fused_kernel<true>,
                        hipFuncAttributeMaxDynamicSharedMemorySize, LDS_BYTES);

    const int gE = (E + 255) / 256;
    const int gA = (n + 15) / 16;
    const int gF = (n + BR - 1) / BR;
    const int nb = (n + 1023) / 1024;
    const int nc4 = (n + 3) / 4;
    const int nx8 = n * D / 8;

    // prep: zero cnt + x->f16 + W->f16 (one kernel), then CSR chain
    prep_kernel<<<1024, 256, 0, stream>>>(x, Wl0, Wr0, Wl1, Wr1, xh, wh,
                                          (int4*)cnt, nc4, nx8);
    count_kernel<<<gE, 256, 0, stream>>>(dstp, cnt, E);
    scan1_kernel<<<nb, 256, 0, stream>>>(cnt, part, n);
    scan3_kernel<<<nb, 256, 0, stream>>>(cnt, part, off, cursor, n, nb);
    fill_kernel<<<gE, 256, 0, stream>>>(srcp, dstp, cursor, adj, E);

    // layer 1: aggregate(xh) -> aggh ; fused writes f16 y1 over xh (row-aliased safe)
    aggregate_kernel<<<gA, 256, 0, stream>>>(xh, adj, off, cnt, aggh, n);
    fused_kernel<false><<<gF, 512, LDS_BYTES, stream>>>(aggh, xh, wh, bl0,
                                                        wh + 16384, g0, be0,
                                                        xh, nullptr, n);
    // layer 2: aggregate(y1h=xh) -> aggh ; fused writes f32 d_out
    aggregate_kernel<<<gA, 256, 0, stream>>>(xh, adj, off, cnt, aggh, n);
    fused_kernel<true><<<gF, 512, LDS_BYTES, stream>>>(aggh, xh, wh + 32768, bl1,
                                                       wh + 49152, g1, be1,
                                                       nullptr, y, n);
}

// Round 15
// 124.261 us; speedup vs baseline: 4.1032x; 1.1736x over previous
//
#include <hip/hip_runtime.h>

#define D 128
#define BR 128   // rows per block in fused kernel

typedef _Float16 f16;
typedef f16 f16x8 __attribute__((ext_vector_type(8)));
typedef float f32x4 __attribute__((ext_vector_type(4)));
typedef unsigned short u16;

// async global->LDS, 16B per lane; LDS dest = wave-uniform base + lane*16
__device__ __forceinline__ void gl_lds16(const f16* g, f16* l) {
    __builtin_amdgcn_global_load_lds(
        (const __attribute__((address_space(1))) void*)g,
        (__attribute__((address_space(3))) void*)l, 16, 0, 0);
}

// merged prep: zero cnt (int4 chunks) + convert x -> f16 + convert 4 W -> f16
__global__ __launch_bounds__(256)
void prep_kernel(const float* __restrict__ x,
                 const float* __restrict__ Wl0, const float* __restrict__ Wr0,
                 const float* __restrict__ Wl1, const float* __restrict__ Wr1,
                 f16* __restrict__ xh, f16* __restrict__ wh,
                 int4* __restrict__ cnt4, int nc4, int nx8) {
    const int nw8 = 2048;                       // 16384/8 chunks per W matrix
    const int total = nc4 + nx8 + 4 * nw8;
    for (int i = blockIdx.x * 256 + threadIdx.x; i < total; i += gridDim.x * 256) {
        if (i < nc4) {
            cnt4[i] = make_int4(0, 0, 0, 0);
        } else if (i < nc4 + nx8) {
            const int j = i - nc4;
            const float4 v0 = *(const float4*)(x + (size_t)j * 8);
            const float4 v1 = *(const float4*)(x + (size_t)j * 8 + 4);
            f16x8 h;
            h[0] = (f16)v0.x; h[1] = (f16)v0.y; h[2] = (f16)v0.z; h[3] = (f16)v0.w;
            h[4] = (f16)v1.x; h[5] = (f16)v1.y; h[6] = (f16)v1.z; h[7] = (f16)v1.w;
            *(f16x8*)(xh + (size_t)j * 8) = h;
        } else {
            const int j = i - nc4 - nx8;
            const int m = j >> 11, o = j & 2047;
            const float* Wsrc = (m == 0) ? Wl0 : (m == 1) ? Wr0 : (m == 2) ? Wl1 : Wr1;
            const float4 v0 = *(const float4*)(Wsrc + o * 8);
            const float4 v1 = *(const float4*)(Wsrc + o * 8 + 4);
            f16x8 h;
            h[0] = (f16)v0.x; h[1] = (f16)v0.y; h[2] = (f16)v0.z; h[3] = (f16)v0.w;
            h[4] = (f16)v1.x; h[5] = (f16)v1.y; h[6] = (f16)v1.z; h[7] = (f16)v1.w;
            *(f16x8*)(wh + m * 16384 + o * 8) = h;
        }
    }
}

// count + per-edge rank: 4 edges/thread (block-strided for coalescing) so 4
// returning atomics are in flight per thread; rank stores coalesced.
__global__ __launch_bounds__(256)
void count_kernel(const int* __restrict__ dst, int* cnt,
                  int* __restrict__ rank, int E) {
    const int base = blockIdx.x * 1024 + threadIdx.x;
    int d[4], r[4];
#pragma unroll
    for (int j = 0; j < 4; ++j) {
        const int e = base + j * 256;
        d[j] = (e < E) ? dst[e] : -1;
    }
#pragma unroll
    for (int j = 0; j < 4; ++j)
        if (d[j] >= 0) r[j] = atomicAdd(&cnt[d[j]], 1);
#pragma unroll
    for (int j = 0; j < 4; ++j) {
        const int e = base + j * 256;
        if (e < E) rank[e] = r[j];
    }
}

// ---- 2-dispatch exclusive scan (R9-proven): scan1 block sums; scan3 base+local ----
__global__ __launch_bounds__(256)
void scan1_kernel(const int* __restrict__ cnt, int* __restrict__ part, int n) {
    const int t = threadIdx.x;
    const int i0 = blockIdx.x * 1024 + t * 4;
    int s = 0;
#pragma unroll
    for (int j = 0; j < 4; ++j) { int i = i0 + j; if (i < n) s += cnt[i]; }
#pragma unroll
    for (int m = 1; m < 64; m <<= 1) s += __shfl_xor(s, m, 64);
    __shared__ int ws[4];
    if ((t & 63) == 0) ws[t >> 6] = s;
    __syncthreads();
    if (t == 0) part[blockIdx.x] = ws[0] + ws[1] + ws[2] + ws[3];
}

__global__ __launch_bounds__(256)
void scan3_kernel(const int* __restrict__ cnt, const int* __restrict__ part,
                  int* __restrict__ off, int n, int nb) {
    const int t = threadIdx.x;
    const int lane = t & 63, wid = t >> 6;
    __shared__ int s_base;
    if (t < 64) {                     // sum of part[j] for j < blockIdx.x
        int s = 0;
        for (int base = 0; base < nb; base += 64) {
            const int idx = base + lane;
            if (idx < nb && idx < (int)blockIdx.x) s += part[idx];
        }
#pragma unroll
        for (int m = 1; m < 64; m <<= 1) s += __shfl_xor(s, m, 64);
        if (lane == 0) s_base = s;
    }
    const int i0 = blockIdx.x * 1024 + t * 4;
    int v[4]; int s = 0;
#pragma unroll
    for (int j = 0; j < 4; ++j) { v[j] = (i0 + j < n) ? cnt[i0 + j] : 0; s += v[j]; }
    int incl = s;
#pragma unroll
    for (int m = 1; m < 64; m <<= 1) {
        int u = __shfl_up(incl, m, 64);
        if (lane >= m) incl += u;
    }
    __shared__ int ws[4];
    if (lane == 63) ws[wid] = incl;
    __syncthreads();
    int woff = 0;
#pragma unroll
    for (int k = 0; k < 4; ++k) woff += (k < wid) ? ws[k] : 0;
    int run = s_base + woff + incl - s;
#pragma unroll
    for (int j = 0; j < 4; ++j) {
        if (i0 + j < n) { off[i0 + j] = run; run += v[j]; }
    }
}

// atomic-free CSR fill: position = off[dst] + rank (precomputed in count).
// Coalesced reads; off[dv] is L2-hot (200KB); scatter store fire-and-forget.
__global__ __launch_bounds__(256)
void fill_kernel(const int* __restrict__ src, const int* __restrict__ dst,
                 const int* __restrict__ rank, const int* __restrict__ off,
                 u16* __restrict__ adj, int E) {
    const int base = blockIdx.x * 1024 + threadIdx.x;
#pragma unroll
    for (int j = 0; j < 4; ++j) {
        const int e = base + j * 256;
        if (e < E) {
            const int dv = dst[e];
            adj[off[dv] + rank[e]] = (u16)src[e];
        }
    }
}

// pull-mode mean aggregation, f16 in/out, f32 accumulate. (R9-proven shape)
// 16 lanes per node (lane owns 8 cols = 16B), 4 nodes/wave, 16 nodes/block,
// 8-neighbor ILP, 8 blocks/CU for latency hiding.
__global__ __launch_bounds__(256, 8)
void aggregate_kernel(const f16* xin, const u16* __restrict__ adj,
                      const int* __restrict__ off, const int* __restrict__ cnt,
                      f16* __restrict__ agg, int n) {
    const int node = blockIdx.x * 16 + (threadIdx.x >> 4);
    if (node >= n) return;
    const int lane = threadIdx.x & 15;
    const int deg = cnt[node];
    const int o = off[node];
    const f16* xp = xin + (lane << 3);
    float a0 = 0.f, a1 = 0.f, a2 = 0.f, a3 = 0.f;
    float a4 = 0.f, a5 = 0.f, a6 = 0.f, a7 = 0.f;
    int k = 0;
    for (; k + 8 <= deg; k += 8) {
        int sidx[8];
#pragma unroll
        for (int j = 0; j < 8; ++j) sidx[j] = adj[o + k + j];
#pragma unroll
        for (int j = 0; j < 8; ++j) {
            const f16x8 v = *(const f16x8*)(xp + (size_t)sidx[j] * D);
            a0 += (float)v[0]; a1 += (float)v[1]; a2 += (float)v[2]; a3 += (float)v[3];
            a4 += (float)v[4]; a5 += (float)v[5]; a6 += (float)v[6]; a7 += (float)v[7];
        }
    }
    for (; k + 4 <= deg; k += 4) {
        int sidx[4];
#pragma unroll
        for (int j = 0; j < 4; ++j) sidx[j] = adj[o + k + j];
#pragma unroll
        for (int j = 0; j < 4; ++j) {
            const f16x8 v = *(const f16x8*)(xp + (size_t)sidx[j] * D);
            a0 += (float)v[0]; a1 += (float)v[1]; a2 += (float)v[2]; a3 += (float)v[3];
            a4 += (float)v[4]; a5 += (float)v[5]; a6 += (float)v[6]; a7 += (float)v[7];
        }
    }
    for (; k < deg; ++k) {
        const f16x8 v = *(const f16x8*)(xp + (size_t)adj[o + k] * D);
        a0 += (float)v[0]; a1 += (float)v[1]; a2 += (float)v[2]; a3 += (float)v[3];
        a4 += (float)v[4]; a5 += (float)v[5]; a6 += (float)v[6]; a7 += (float)v[7];
    }
    const float s = 1.0f / (float)max(deg, 1);
    f16x8 r;
    r[0] = (f16)(a0 * s); r[1] = (f16)(a1 * s);
    r[2] = (f16)(a2 * s); r[3] = (f16)(a3 * s);
    r[4] = (f16)(a4 * s); r[5] = (f16)(a5 * s);
    r[6] = (f16)(a6 * s); r[7] = (f16)(a7 * s);
    *(f16x8*)(agg + (size_t)node * D + (lane << 3)) = r;
}

// fused: out = agg @ Wl^T + bl + xin @ Wr^T ; LayerNorm ; ReLU  (R9-proven shape)
// 512 threads = 8 waves; wave w owns rows [w*16, w*16+16) of the 128-row tile.
// Staging: global_load_lds width=16, LINEAR LDS dest + inverse-XOR-swizzled
// global source (granule kg ^= row&7); reads use the same involution.
template <bool LAST>
__global__ __launch_bounds__(512, 2)
void fused_kernel(const f16* __restrict__ aggh, const f16* xinh,
                  const f16* __restrict__ Whl, const float* __restrict__ bl,
                  const f16* __restrict__ Whr,
                  const float* __restrict__ gamma, const float* __restrict__ beta,
                  f16* yh, float* __restrict__ yf, int n) {
    extern __shared__ char lds_raw[];
    f16* As = (f16*)lds_raw;             // [128][128] swizzled (32 KB)
    f16* Ws = (f16*)(lds_raw + 32768);   // [128][128] swizzled (32 KB)
    const int tid = threadIdx.x;
    const int w = tid >> 6, l = tid & 63;
    const int c = l & 15, g = l >> 4;
    const int lrow = l >> 4, kgs = l & 15;
    const int row0 = blockIdx.x * BR;

    f32x4 acc[8];
#pragma unroll
    for (int jt = 0; jt < 8; ++jt) acc[jt] = (f32x4){0.f, 0.f, 0.f, 0.f};

    for (int pass = 0; pass < 2; ++pass) {
        if (pass) __syncthreads();       // all pass-0 LDS reads done before overwrite
        const f16* Ain = pass ? xinh : aggh;
        const f16* Win = pass ? Whr : Whl;
#pragma unroll
        for (int i = 0; i < 4; ++i) {
            const int rbase = i * 32 + w * 4;         // wave-uniform (w uniform in wave)
            const int row = rbase + lrow;
            const int kg = kgs ^ (row & 7);           // inverse swizzle on source
            int srow = row0 + row;
            if (srow >= n) srow = n - 1;              // clamp: garbage only feeds rows>=n
            gl_lds16(Ain + (size_t)srow * D + kg * 8, As + rbase * D);
            gl_lds16(Win + row * D + kg * 8, Ws + rbase * D);
        }
        __syncthreads();                 // drains vmcnt -> LDS tiles complete
#pragma unroll
        for (int ks = 0; ks < 4; ++ks) {
            const int ke = ks * 32 + g * 8;
            const int ar = w * 16 + c;
            const f16x8 av = *(const f16x8*)(As + ar * D + (ke ^ ((ar & 7) * 8)));
            f16x8 bv[8];
#pragma unroll
            for (int jt = 0; jt < 8; ++jt) {
                const int br = jt * 16 + c;
                bv[jt] = *(const f16x8*)(Ws + br * D + (ke ^ ((br & 7) * 8)));
            }
#pragma unroll
            for (int jt = 0; jt < 8; ++jt)
                acc[jt] = __builtin_amdgcn_mfma_f32_16x16x32_f16(
                    av, bv[jt], acc[jt], 0, 0, 0);
        }
    }

    // epilogue: bias + LayerNorm + ReLU. C/D layout: col=l&15, row=(l>>4)*4+reg.
    float bj[8], gj[8], btj[8];
#pragma unroll
    for (int jt = 0; jt < 8; ++jt) {
        const int j = jt * 16 + c;
        bj[jt] = bl[j]; gj[jt] = gamma[j]; btj[jt] = beta[j];
    }
#pragma unroll
    for (int reg = 0; reg < 4; ++reg) {
        float v[8]; float s1 = 0.f, s2 = 0.f;
#pragma unroll
        for (int jt = 0; jt < 8; ++jt) {
            v[jt] = acc[jt][reg] + bj[jt];
            s1 += v[jt];
            s2 = fmaf(v[jt], v[jt], s2);
        }
#pragma unroll
        for (int m = 1; m < 16; m <<= 1) {
            s1 += __shfl_xor(s1, m, 64);
            s2 += __shfl_xor(s2, m, 64);
        }
        const float mu = s1 * (1.f / 128.f);
        const float var = s2 * (1.f / 128.f) - mu * mu;
        const float rstd = rsqrtf(var + 1e-5f);
        const int row = row0 + w * 16 + g * 4 + reg;
        if (row < n) {
#pragma unroll
            for (int jt = 0; jt < 8; ++jt) {
                const float o = fmaxf((v[jt] - mu) * rstd * gj[jt] + btj[jt], 0.f);
                if (LAST) yf[(size_t)row * D + jt * 16 + c] = o;
                else      yh[(size_t)row * D + jt * 16 + c] = (f16)o;
            }
        }
    }
}

extern "C" void kernel_launch(void* const* d_in, const int* in_sizes, int n_in,
                              void* d_out, int out_size, void* d_ws, size_t ws_size,
                              hipStream_t stream) {
    const float* x   = (const float*)d_in[0];
    const int*   ei  = (const int*)d_in[1];
    const int E = in_sizes[1] / 2;
    const int n = in_sizes[0] / D;
    const int* srcp = ei;
    const int* dstp = ei + E;
    const float* Wl0 = (const float*)d_in[2];
    const float* bl0 = (const float*)d_in[3];
    const float* Wr0 = (const float*)d_in[4];
    const float* g0  = (const float*)d_in[5];
    const float* be0 = (const float*)d_in[6];
    const float* Wl1 = (const float*)d_in[7];
    const float* bl1 = (const float*)d_in[8];
    const float* Wr1 = (const float*)d_in[9];
    const float* g1  = (const float*)d_in[10];
    const float* be1 = (const float*)d_in[11];
    float* y = (float*)d_out;

    // workspace: cnt | off | part | rank(E int) | adj(u16) | wh | aggh | xh(=y1h)
    char* ws = (char*)d_ws;
    const size_t aN  = ((size_t)n * 4 + 255) & ~(size_t)255;
    const size_t aP  = 4096;
    const size_t aR  = ((size_t)E * 4 + 255) & ~(size_t)255;   // rank
    const size_t aE2 = ((size_t)E * 2 + 255) & ~(size_t)255;   // u16 adj
    const size_t aW  = 4 * 16384 * 2;                          // 4 W matrices, f16
    const size_t aH  = ((size_t)n * D * 2 + 255) & ~(size_t)255;
    int* cnt  = (int*)ws;
    int* off  = (int*)(ws + aN);
    int* part = (int*)(ws + 2 * aN);
    int* rank = (int*)(ws + 2 * aN + aP);
    u16* adj  = (u16*)(ws + 2 * aN + aP + aR);
    f16* wh   = (f16*)(ws + 2 * aN + aP + aR + aE2);
    f16* aggh = (f16*)(ws + 2 * aN + aP + aR + aE2 + aW);
    f16* xh   = (f16*)(ws + 2 * aN + aP + aR + aE2 + aW + aH);
    const size_t need = 2 * aN + aP + aR + aE2 + aW + 2 * aH;
    if (ws_size < need) return;

    const int LDS_BYTES = 65536;
    hipFuncSetAttribute((const void*)fused_kernel<false>,
                        hipFuncAttributeMaxDynamicSharedMemorySize, LDS_BYTES);
    hipFuncSetAttribute((const void*)fused_kernel<true>,
                        hipFuncAttributeMaxDynamicSharedMemorySize, LDS_BYTES);

    const int gE4 = (E + 1023) / 1024;   // 4 edges per thread
    const int gA  = (n + 15) / 16;
    const int gF  = (n + BR - 1) / BR;
    const int nb  = (n + 1023) / 1024;
    const int nc4 = (n + 3) / 4;
    const int nx8 = n * D / 8;

    // prep: zero cnt + x->f16 + W->f16 (one kernel), then CSR chain
    prep_kernel<<<1024, 256, 0, stream>>>(x, Wl0, Wr0, Wl1, Wr1, xh, wh,
                                          (int4*)cnt, nc4, nx8);
    count_kernel<<<gE4, 256, 0, stream>>>(dstp, cnt, rank, E);
    scan1_kernel<<<nb, 256, 0, stream>>>(cnt, part, n);
    scan3_kernel<<<nb, 256, 0, stream>>>(cnt, part, off, n, nb);
    fill_kernel<<<gE4, 256, 0, stream>>>(srcp, dstp, rank, off, adj, E);

    // layer 1: aggregate(xh) -> aggh ; fused writes f16 y1 over xh (row-aliased safe)
    aggregate_kernel<<<gA, 256, 0, stream>>>(xh, adj, off, cnt, aggh, n);
    fused_kernel<false><<<gF, 512, LDS_BYTES, stream>>>(aggh, xh, wh, bl0,
                                                        wh + 16384, g0, be0,
                                                        xh, nullptr, n);
    // layer 2: aggregate(y1h=xh) -> aggh ; fused writes f32 d_out
    aggregate_kernel<<<gA, 256, 0, stream>>>(xh, adj, off, cnt, aggh, n);
    fused_kernel<true><<<gF, 512, LDS_BYTES, stream>>>(aggh, xh, wh + 32768, bl1,
                                                       wh + 49152, g1, be1,
                                                       nullptr, y, n);
}